// Round 4
// baseline (225.513 us; speedup 1.0000x reference)
//
#include <hip/hip_runtime.h>
#include <hip/hip_bf16.h>

typedef __bf16 bf16_t;
typedef __bf16 bf16x8 __attribute__((ext_vector_type(8)));
typedef float f32x4 __attribute__((ext_vector_type(4)));
typedef float f32x16 __attribute__((ext_vector_type(16)));
typedef unsigned int u32x4 __attribute__((ext_vector_type(4)));

#define MFMA16(A,B,C) __builtin_amdgcn_mfma_f32_16x16x32_bf16(A,B,C,0,0,0)
#define MFMA32(A,B,C) __builtin_amdgcn_mfma_f32_32x32x16_bf16(A,B,C,0,0,0)

// exp(s/8) computed as exp2(s * 0.125*log2(e)); the scale is folded into Q.
#define QSCALE 0.18033688011112042f

__device__ inline unsigned pk_bf16(float lo, float hi) {
  unsigned r;
  asm("v_cvt_pk_bf16_f32 %0, %1, %2" : "=v"(r) : "v"(lo), "v"(hi));
  return r;
}
__device__ inline bf16x8 frag4(unsigned a, unsigned b, unsigned c, unsigned d) {
  union { u32x4 u; bf16x8 f; } x;
  x.u = (u32x4){a, b, c, d};
  return x.f;
}

// ---------------------------------------------------------------------------
// Kernel 1: qkv = w_in @ x + b_in   (per batch GEMM [192x512] x [512x4096])
// Q -> q_r [8][4096][64] bf16, PRE-SCALED by 0.125*log2(e)
// K -> k_r [8][4096][64] bf16
// V -> v_t [8][64][4096] bf16 (channel-major)
// ---------------------------------------------------------------------------
__global__ __launch_bounds__(256) void qkv_kernel(
    const float* __restrict__ x,
    const float* __restrict__ w_in,
    const float* __restrict__ b_in,
    bf16_t* __restrict__ q_r,
    bf16_t* __restrict__ k_r,
    bf16_t* __restrict__ v_t)
{
    const int b    = blockIdx.z;
    const int mt   = blockIdx.y;          // 0:Q 1:K 2:V
    const int n0   = blockIdx.x * 64;
    const int t    = threadIdx.x;
    const int lane = t & 63;
    const int wave = t >> 6;
    const int wm   = wave >> 1;
    const int wn   = wave & 1;

    __shared__ bf16_t Xs[64][56];

    const float* xb = x + (size_t)b * 512 * 4096;

    f32x4 acc[2][2] = {};

    for (int k0 = 0; k0 < 512; k0 += 32) {
        __syncthreads();
        {
            const int c  = t >> 3;
            const int nb = (t & 7) * 8;
            const float* src = xb + (size_t)(k0 + c) * 4096 + n0 + nb;
            float4 v0 = *(const float4*)(src);
            float4 v1 = *(const float4*)(src + 4);
            Xs[nb + 0][c] = (bf16_t)v0.x; Xs[nb + 1][c] = (bf16_t)v0.y;
            Xs[nb + 2][c] = (bf16_t)v0.z; Xs[nb + 3][c] = (bf16_t)v0.w;
            Xs[nb + 4][c] = (bf16_t)v1.x; Xs[nb + 5][c] = (bf16_t)v1.y;
            Xs[nb + 6][c] = (bf16_t)v1.z; Xs[nb + 7][c] = (bf16_t)v1.w;
        }
        __syncthreads();

        bf16x8 afrag[2];
        #pragma unroll
        for (int mf = 0; mf < 2; ++mf) {
            const int m = mt * 64 + wm * 32 + mf * 16 + (lane & 15);
            const float* wsrc = w_in + (size_t)m * 512 + k0 + (lane >> 4) * 8;
            float4 a0 = *(const float4*)(wsrc);
            float4 a1 = *(const float4*)(wsrc + 4);
            bf16x8 af;
            af[0] = (bf16_t)a0.x; af[1] = (bf16_t)a0.y; af[2] = (bf16_t)a0.z; af[3] = (bf16_t)a0.w;
            af[4] = (bf16_t)a1.x; af[5] = (bf16_t)a1.y; af[6] = (bf16_t)a1.z; af[7] = (bf16_t)a1.w;
            afrag[mf] = af;
        }
        #pragma unroll
        for (int nf = 0; nf < 2; ++nf) {
            const int n = wn * 32 + nf * 16 + (lane & 15);
            bf16x8 bfrag = *(const bf16x8*)&Xs[n][(lane >> 4) * 8];
            #pragma unroll
            for (int mf = 0; mf < 2; ++mf)
                acc[mf][nf] = MFMA16(afrag[mf], bfrag, acc[mf][nf]);
        }
    }

    #pragma unroll
    for (int mf = 0; mf < 2; ++mf) {
        #pragma unroll
        for (int nf = 0; nf < 2; ++nf) {
            const int cloc = wm * 32 + mf * 16 + (lane >> 4) * 4;
            const int m    = mt * 64 + cloc;
            const int n    = n0 + wn * 32 + nf * 16 + (lane & 15);
            #pragma unroll
            for (int r = 0; r < 4; ++r) {
                float val = acc[mf][nf][r] + b_in[m + r];
                if (mt == 0) {
                    val *= QSCALE;
                    q_r[((size_t)b * 4096 + n) * 64 + cloc + r] = (bf16_t)val;
                } else if (mt == 1) {
                    k_r[((size_t)b * 4096 + n) * 64 + cloc + r] = (bf16_t)val;
                } else {
                    v_t[((size_t)b * 64 + cloc + r) * 4096 + n] = (bf16_t)val;
                }
            }
        }
    }
}

// ---------------------------------------------------------------------------
// Kernel 2: flash attention PARTIAL (KV-split by 4), REGISTER-DIRECT version.
// No LDS, no barriers: each wave independent, K/V fragments loaded straight
// from global (16B contiguous per lane; L1/L2 serve cross-wave redundancy).
// Grid: (32 q-tiles, 8 batches, 4 splits) = 1024 blocks, 256 threads.
// Per wave: 32 q-rows x 1024 kv, processed in 32-kv subtiles.
// K frags prefetched one subtile ahead (manual 2-unroll, named reg sets).
// ---------------------------------------------------------------------------
__global__ __launch_bounds__(256, 4) void attn_partial_kernel(
    const bf16_t* __restrict__ q_r, const bf16_t* __restrict__ k_r,
    const bf16_t* __restrict__ v_t,
    bf16_t* __restrict__ Opart, float* __restrict__ ml)
{
    const int b     = blockIdx.y;
    const int split = blockIdx.z;
    const int kv0   = split * 1024;
    const int t     = threadIdx.x;
    const int lane  = t & 63;
    const int wave  = t >> 6;
    const int lq    = lane & 31;
    const int hi    = lane >> 5;
    const int nq    = blockIdx.x * 128 + wave * 32 + lq;

    // lane-fixed base pointers
    const bf16_t* kptr = k_r + ((size_t)b * 4096 + lq) * 64 + hi * 8;
    const bf16_t* vptr = v_t + ((size_t)b * 64 + lq) * 4096 + hi * 8;

    // Q fragments (entire d=64 in 4 k-steps), pre-scaled in qkv
    bf16x8 qf[4];
    {
        const bf16_t* qp = q_r + ((size_t)b * 4096 + nq) * 64 + hi * 8;
        #pragma unroll
        for (int ks = 0; ks < 4; ++ks) qf[ks] = *(const bf16x8*)(qp + ks * 16);
    }

    f32x16 oa0 = {}, oa1 = {};        // O^T accum: rows=channels (ct*32+...), col=q
    float m_run = -3.0e38f, l_run = 0.f;

    bf16x8 kfA[4], kfB[4];
    #pragma unroll
    for (int ks = 0; ks < 4; ++ks)
        kfA[ks] = *(const bf16x8*)(kptr + (size_t)kv0 * 64 + ks * 16);

    // one 32-kv subtile; kcur holds this subtile's K frags, knext gets kvn's
    auto SUBTILE = [&](bf16x8 (&kcur)[4], bf16x8 (&knext)[4], int kvb) {
        const int kvn = (kvb + 32 < kv0 + 1024) ? (kvb + 32) : kv0;  // last: dummy

        // V frags for this subtile (issued early; PV consumes after softmax)
        const bf16x8 vf00 = *(const bf16x8*)(vptr + kvb);
        const bf16x8 vf01 = *(const bf16x8*)(vptr + kvb + 16);
        const bf16x8 vf10 = *(const bf16x8*)(vptr + (size_t)32 * 4096 + kvb);
        const bf16x8 vf11 = *(const bf16x8*)(vptr + (size_t)32 * 4096 + kvb + 16);
        // prefetch next subtile's K frags
        #pragma unroll
        for (int ks = 0; ks < 4; ++ks)
            knext[ks] = *(const bf16x8*)(kptr + (size_t)kvn * 64 + ks * 16);

        // --- QK^T: S^T[kv][q] for 32 kv rows ---
        f32x16 s = {};
        #pragma unroll
        for (int ks = 0; ks < 4; ++ks) s = MFMA32(kcur[ks], qf[ks], s);

        // --- online softmax, log2 domain, defer-max THR=8 ---
        {
            float a8[8];
            #pragma unroll
            for (int r = 0; r < 8; ++r) a8[r] = fmaxf(s[r], s[r + 8]);
            #pragma unroll
            for (int r = 0; r < 4; ++r) a8[r] = fmaxf(a8[r], a8[r + 4]);
            float tm = fmaxf(fmaxf(a8[0], a8[1]), fmaxf(a8[2], a8[3]));
            tm = fmaxf(tm, __shfl_xor(tm, 32));
            if (__any(tm > m_run + 8.f)) {
                const float nm = fmaxf(m_run, tm);
                const float sc = __builtin_amdgcn_exp2f(m_run - nm);
                m_run = nm;
                l_run *= sc;
                #pragma unroll
                for (int r = 0; r < 16; ++r) { oa0[r] *= sc; oa1[r] *= sc; }
            }
        }
        #pragma unroll
        for (int r = 0; r < 16; ++r) s[r] = __builtin_amdgcn_exp2f(s[r] - m_run);
        {
            float a8[8];
            #pragma unroll
            for (int r = 0; r < 8; ++r) a8[r] = s[r] + s[r + 8];
            #pragma unroll
            for (int r = 0; r < 4; ++r) a8[r] += a8[r + 4];
            float ps = (a8[0] + a8[1]) + (a8[2] + a8[3]);
            ps += __shfl_xor(ps, 32);
            l_run += ps;
        }

        // --- pack P -> bf16 B-frags (half-wave exchange) ---
        const unsigned w0 = pk_bf16(s[0], s[1]),   w1 = pk_bf16(s[2], s[3]);
        const unsigned w2 = pk_bf16(s[4], s[5]),   w3 = pk_bf16(s[6], s[7]);
        const unsigned w4 = pk_bf16(s[8], s[9]),   w5 = pk_bf16(s[10], s[11]);
        const unsigned w6 = pk_bf16(s[12], s[13]), w7 = pk_bf16(s[14], s[15]);
        const unsigned e0 = __shfl_xor((int)(hi ? w0 : w2), 32);
        const unsigned e1 = __shfl_xor((int)(hi ? w1 : w3), 32);
        const unsigned e2 = __shfl_xor((int)(hi ? w4 : w6), 32);
        const unsigned e3 = __shfl_xor((int)(hi ? w5 : w7), 32);
        const bf16x8 pf0 = frag4(hi ? e0 : w0, hi ? e1 : w1, hi ? w2 : e0, hi ? w3 : e1);
        const bf16x8 pf1 = frag4(hi ? e2 : w4, hi ? e3 : w5, hi ? w6 : e2, hi ? w7 : e3);

        // --- PV: O^T += V^T P^T ---
        oa0 = MFMA32(vf00, pf0, oa0);
        oa0 = MFMA32(vf01, pf1, oa0);
        oa1 = MFMA32(vf10, pf0, oa1);
        oa1 = MFMA32(vf11, pf1, oa1);
    };

    for (int it = 0; it < 16; ++it) {
        SUBTILE(kfA, kfB, kv0 + it * 64);
        SUBTILE(kfB, kfA, kv0 + it * 64 + 32);
    }

    // --- epilogue: normalize, pack to B-frag order, store partials ---
    const float inv = 1.f / l_run;
    bf16x8 obf[4];
    #pragma unroll
    for (int ct = 0; ct < 2; ++ct) {
        f32x16 o = ct ? oa1 : oa0;
        #pragma unroll
        for (int r = 0; r < 16; ++r) o[r] *= inv;
        const unsigned w0 = pk_bf16(o[0], o[1]),   w1 = pk_bf16(o[2], o[3]);
        const unsigned w2 = pk_bf16(o[4], o[5]),   w3 = pk_bf16(o[6], o[7]);
        const unsigned w4 = pk_bf16(o[8], o[9]),   w5 = pk_bf16(o[10], o[11]);
        const unsigned w6 = pk_bf16(o[12], o[13]), w7 = pk_bf16(o[14], o[15]);
        const unsigned e0 = __shfl_xor((int)(hi ? w0 : w2), 32);
        const unsigned e1 = __shfl_xor((int)(hi ? w1 : w3), 32);
        const unsigned e2 = __shfl_xor((int)(hi ? w4 : w6), 32);
        const unsigned e3 = __shfl_xor((int)(hi ? w5 : w7), 32);
        obf[ct * 2 + 0] = frag4(hi ? e0 : w0, hi ? e1 : w1, hi ? w2 : e0, hi ? w3 : e1);
        obf[ct * 2 + 1] = frag4(hi ? e2 : w4, hi ? e3 : w5, hi ? w6 : e2, hi ? w7 : e3);
    }

    bf16_t* op = Opart + (((size_t)(b * 4 + split)) * 4096 + nq) * 64;
    #pragma unroll
    for (int ks = 0; ks < 4; ++ks)
        *(bf16x8*)(op + ks * 16 + hi * 8) = obf[ks];
    if (hi == 0) {
        float2 v; v.x = m_run; v.y = l_run;
        *(float2*)&ml[(((size_t)(b * 4 + split)) * 4096 + nq) * 2] = v;
    }
}

// ---------------------------------------------------------------------------
// Kernel 3: combine partials + out-proj + bias + skip.
// Grid: (64 q-tiles of 64, 8 batches) = 512 blocks, 512 threads (8 waves).
// ---------------------------------------------------------------------------
__global__ __launch_bounds__(512) void combine_kernel(
    const bf16_t* __restrict__ Opart, const float* __restrict__ ml,
    const float* __restrict__ x, const float* __restrict__ w_out,
    const float* __restrict__ b_out, float* __restrict__ y)
{
    const int b    = blockIdx.y;
    const int t    = threadIdx.x;
    const int lane = t & 63;
    const int wave = t >> 6;          // 0..7
    const int lq   = lane & 31;
    const int hi   = lane >> 5;
    const int group = wave >> 2;      // 0..1
    const int nq   = blockIdx.x * 64 + group * 32 + lq;

    float coef[4];
    {
        float m_s[4], l_s[4];
        #pragma unroll
        for (int s = 0; s < 4; ++s) {
            float2 v = *(const float2*)&ml[(((size_t)(b * 4 + s)) * 4096 + nq) * 2];
            m_s[s] = v.x; l_s[s] = v.y;
        }
        const float M = fmaxf(fmaxf(m_s[0], m_s[1]), fmaxf(m_s[2], m_s[3]));
        float L = 0.f;
        #pragma unroll
        for (int s = 0; s < 4; ++s) {
            coef[s] = __builtin_amdgcn_exp2f(m_s[s] - M) * l_s[s];
            L += coef[s];
        }
        const float invL = 1.f / L;
        #pragma unroll
        for (int s = 0; s < 4; ++s) coef[s] *= invL;
    }

    bf16x8 obf[4];
    #pragma unroll
    for (int ks = 0; ks < 4; ++ks) {
        float a8[8] = {};
        #pragma unroll
        for (int s = 0; s < 4; ++s) {
            bf16x8 o = *(const bf16x8*)&Opart[
                (((size_t)(b * 4 + s)) * 4096 + nq) * 64 + ks * 16 + hi * 8];
            #pragma unroll
            for (int j = 0; j < 8; ++j) a8[j] += coef[s] * (float)o[j];
        }
        obf[ks] = frag4(pk_bf16(a8[0], a8[1]), pk_bf16(a8[2], a8[3]),
                        pk_bf16(a8[4], a8[5]), pk_bf16(a8[6], a8[7]));
    }

    #pragma unroll 1
    for (int i = 0; i < 4; ++i) {
        const int mt = (wave & 3) * 4 + i;
        f32x16 acc = {};
        #pragma unroll
        for (int ks = 0; ks < 4; ++ks) {
            const float* wp = w_out + (size_t)(mt * 32 + lq) * 64 + ks * 16 + hi * 8;
            float4 a0 = *(const float4*)wp;
            float4 a1 = *(const float4*)(wp + 4);
            bf16x8 af = frag4(pk_bf16(a0.x, a0.y), pk_bf16(a0.z, a0.w),
                              pk_bf16(a1.x, a1.y), pk_bf16(a1.z, a1.w));
            acc = MFMA32(af, obf[ks], acc);
        }
        #pragma unroll
        for (int r = 0; r < 16; ++r) {
            const int m = mt * 32 + (r & 3) + 8 * (r >> 2) + 4 * hi;
            const size_t idx = ((size_t)b * 512 + m) * 4096 + nq;
            y[idx] = acc[r] + b_out[m] + x[idx];
        }
    }
}

// ---------------------------------------------------------------------------
extern "C" void kernel_launch(void* const* d_in, const int* in_sizes, int n_in,
                              void* d_out, int out_size, void* d_ws, size_t ws_size,
                              hipStream_t stream)
{
    const float* x     = (const float*)d_in[0];
    const float* w_in  = (const float*)d_in[1];
    const float* b_in  = (const float*)d_in[2];
    const float* w_out = (const float*)d_in[3];
    const float* b_out = (const float*)d_in[4];
    float* y = (float*)d_out;

    char* ws = (char*)d_ws;
    bf16_t* q_r   = (bf16_t*)(ws);                   // 4 MiB
    bf16_t* k_r   = (bf16_t*)(ws + 4194304);         // 4 MiB
    bf16_t* v_t   = (bf16_t*)(ws + 8388608);         // 4 MiB
    bf16_t* Opart = (bf16_t*)(ws + 12582912);        // 8*4*4096*64*2 = 16 MiB
    float*  ml    = (float*)(ws + 29360128);         // 8*4*4096*2*4  = 1 MiB

    qkv_kernel<<<dim3(64, 3, 8), 256, 0, stream>>>(x, w_in, b_in, q_r, k_r, v_t);
    attn_partial_kernel<<<dim3(32, 8, 4), 256, 0, stream>>>(q_r, k_r, v_t, Opart, ml);
    combine_kernel<<<dim3(64, 8), 512, 0, stream>>>(Opart, ml, x, w_out, b_out, y);
}

// Round 5
// 155.906 us; speedup vs baseline: 1.4465x; 1.4465x over previous
//
#include <hip/hip_runtime.h>
#include <hip/hip_bf16.h>

typedef __bf16 bf16_t;
typedef __bf16 bf16x8 __attribute__((ext_vector_type(8)));
typedef float f32x4 __attribute__((ext_vector_type(4)));
typedef float f32x16 __attribute__((ext_vector_type(16)));
typedef unsigned int u32x4 __attribute__((ext_vector_type(4)));

#define MFMA16(A,B,C) __builtin_amdgcn_mfma_f32_16x16x32_bf16(A,B,C,0,0,0)
#define MFMA32(A,B,C) __builtin_amdgcn_mfma_f32_32x32x16_bf16(A,B,C,0,0,0)

// exp(s/8) computed as exp2(s * 0.125*log2(e)); the scale is folded into Q.
#define QSCALE 0.18033688011112042f

__device__ inline unsigned pk_bf16(float lo, float hi) {
  unsigned r;
  asm("v_cvt_pk_bf16_f32 %0, %1, %2" : "=v"(r) : "v"(lo), "v"(hi));
  return r;
}
__device__ inline bf16x8 frag4(unsigned a, unsigned b, unsigned c, unsigned d) {
  union { u32x4 u; bf16x8 f; } x;
  x.u = (u32x4){a, b, c, d};
  return x.f;
}
__device__ inline void gload16(const bf16_t* g, const bf16_t* l) {
  __builtin_amdgcn_global_load_lds(
      (const __attribute__((address_space(1))) unsigned int*)g,
      (__attribute__((address_space(3))) unsigned int*)l, 16, 0, 0);
}

// ---------------------------------------------------------------------------
// Kernel 1: qkv = w_in @ x + b_in   (per batch GEMM [192x512] x [512x4096])
// Q -> q_r [8][4096][64] bf16, PRE-SCALED by 0.125*log2(e)
// K -> k_r [8][4096][64] bf16
// V -> v_t [8][64][4096] bf16 (channel-major)
// ---------------------------------------------------------------------------
__global__ __launch_bounds__(256) void qkv_kernel(
    const float* __restrict__ x,
    const float* __restrict__ w_in,
    const float* __restrict__ b_in,
    bf16_t* __restrict__ q_r,
    bf16_t* __restrict__ k_r,
    bf16_t* __restrict__ v_t)
{
    const int b    = blockIdx.z;
    const int mt   = blockIdx.y;          // 0:Q 1:K 2:V
    const int n0   = blockIdx.x * 64;
    const int t    = threadIdx.x;
    const int lane = t & 63;
    const int wave = t >> 6;
    const int wm   = wave >> 1;
    const int wn   = wave & 1;

    __shared__ bf16_t Xs[64][56];

    const float* xb = x + (size_t)b * 512 * 4096;

    f32x4 acc[2][2] = {};

    for (int k0 = 0; k0 < 512; k0 += 32) {
        __syncthreads();
        {
            const int c  = t >> 3;
            const int nb = (t & 7) * 8;
            const float* src = xb + (size_t)(k0 + c) * 4096 + n0 + nb;
            float4 v0 = *(const float4*)(src);
            float4 v1 = *(const float4*)(src + 4);
            Xs[nb + 0][c] = (bf16_t)v0.x; Xs[nb + 1][c] = (bf16_t)v0.y;
            Xs[nb + 2][c] = (bf16_t)v0.z; Xs[nb + 3][c] = (bf16_t)v0.w;
            Xs[nb + 4][c] = (bf16_t)v1.x; Xs[nb + 5][c] = (bf16_t)v1.y;
            Xs[nb + 6][c] = (bf16_t)v1.z; Xs[nb + 7][c] = (bf16_t)v1.w;
        }
        __syncthreads();

        bf16x8 afrag[2];
        #pragma unroll
        for (int mf = 0; mf < 2; ++mf) {
            const int m = mt * 64 + wm * 32 + mf * 16 + (lane & 15);
            const float* wsrc = w_in + (size_t)m * 512 + k0 + (lane >> 4) * 8;
            float4 a0 = *(const float4*)(wsrc);
            float4 a1 = *(const float4*)(wsrc + 4);
            bf16x8 af;
            af[0] = (bf16_t)a0.x; af[1] = (bf16_t)a0.y; af[2] = (bf16_t)a0.z; af[3] = (bf16_t)a0.w;
            af[4] = (bf16_t)a1.x; af[5] = (bf16_t)a1.y; af[6] = (bf16_t)a1.z; af[7] = (bf16_t)a1.w;
            afrag[mf] = af;
        }
        #pragma unroll
        for (int nf = 0; nf < 2; ++nf) {
            const int n = wn * 32 + nf * 16 + (lane & 15);
            bf16x8 bfrag = *(const bf16x8*)&Xs[n][(lane >> 4) * 8];
            #pragma unroll
            for (int mf = 0; mf < 2; ++mf)
                acc[mf][nf] = MFMA16(afrag[mf], bfrag, acc[mf][nf]);
        }
    }

    #pragma unroll
    for (int mf = 0; mf < 2; ++mf) {
        #pragma unroll
        for (int nf = 0; nf < 2; ++nf) {
            const int cloc = wm * 32 + mf * 16 + (lane >> 4) * 4;
            const int m    = mt * 64 + cloc;
            const int n    = n0 + wn * 32 + nf * 16 + (lane & 15);
            #pragma unroll
            for (int r = 0; r < 4; ++r) {
                float val = acc[mf][nf][r] + b_in[m + r];
                if (mt == 0) {
                    val *= QSCALE;
                    q_r[((size_t)b * 4096 + n) * 64 + cloc + r] = (bf16_t)val;
                } else if (mt == 1) {
                    k_r[((size_t)b * 4096 + n) * 64 + cloc + r] = (bf16_t)val;
                } else {
                    v_t[((size_t)b * 64 + cloc + r) * 4096 + n] = (bf16_t)val;
                }
            }
        }
    }
}

// ---------------------------------------------------------------------------
// Kernel 2: flash attention PARTIAL (KV-split by 4), LDS-staged, 64 q/wave.
// Grid: (16 q-tiles of 256, 8 batches, 4 splits) = 512 blocks, 256 threads.
// Each wave owns TWO 32-q column blocks (qA = base+lq, qB = qA+32) sharing
// the same K/V LDS fragments -> 32 MFMA per 16 ds_read_b128 per 64-kv tile.
// Online softmax at 32-kv granularity (register relief), defer-max THR=8.
// ---------------------------------------------------------------------------
__global__ __launch_bounds__(256, 2) void attn_partial_kernel(
    const bf16_t* __restrict__ q_r, const bf16_t* __restrict__ k_r,
    const bf16_t* __restrict__ v_t,
    bf16_t* __restrict__ Opart, float* __restrict__ ml)
{
    const int b     = blockIdx.y;
    const int split = blockIdx.z;
    const int kv0   = split * 1024;
    const int t     = threadIdx.x;
    const int lane  = t & 63;
    const int wave  = t >> 6;
    const int lq    = lane & 31;
    const int hi    = lane >> 5;
    const int qA    = blockIdx.x * 256 + wave * 64 + lq;
    const int qB    = qA + 32;

    __shared__ bf16_t Ks[2][64 * 64];
    __shared__ bf16_t Vs[2][64 * 64];

    const int r8  = lane >> 3;
    const int csw = (lane & 7) ^ r8;
    const bf16_t* kb = k_r + (size_t)b * 4096 * 64;
    const bf16_t* vb = v_t + (size_t)b * 64 * 4096;

    auto STAGE = [&](int buf, int m0) {
        #pragma unroll
        for (int i = 0; i < 2; ++i) {
            const int rr = wave * 16 + i * 8;
            gload16(kb + (size_t)(m0 + rr + r8) * 64 + csw * 8, &Ks[buf][rr * 64]);
            gload16(vb + (size_t)(rr + r8) * 4096 + m0 + csw * 8, &Vs[buf][rr * 64]);
        }
    };

    // Q fragments for both q-blocks (pre-scaled in qkv)
    bf16x8 qfA[4], qfB[4];
    {
        const bf16_t* qpA = q_r + ((size_t)b * 4096 + qA) * 64 + hi * 8;
        const bf16_t* qpB = q_r + ((size_t)b * 4096 + qB) * 64 + hi * 8;
        #pragma unroll
        for (int ks = 0; ks < 4; ++ks) {
            qfA[ks] = *(const bf16x8*)(qpA + ks * 16);
            qfB[ks] = *(const bf16x8*)(qpB + ks * 16);
        }
    }

    f32x16 oaA0 = {}, oaA1 = {}, oaB0 = {}, oaB1 = {};
    float mA = -3.0e38f, lA = 0.f, mB = -3.0e38f, lB = 0.f;

    // softmax + pack + PV for one 32-kv subtile of one q-block
    auto SMPV = [&](f32x16& s, float& m_run, float& l_run,
                    f32x16& o0, f32x16& o1,
                    const bf16x8 v00, const bf16x8 v01,
                    const bf16x8 v10, const bf16x8 v11) {
        {
            float a8[8];
            #pragma unroll
            for (int r = 0; r < 8; ++r) a8[r] = fmaxf(s[r], s[r + 8]);
            #pragma unroll
            for (int r = 0; r < 4; ++r) a8[r] = fmaxf(a8[r], a8[r + 4]);
            float tm = fmaxf(fmaxf(a8[0], a8[1]), fmaxf(a8[2], a8[3]));
            tm = fmaxf(tm, __shfl_xor(tm, 32));
            if (__any(tm > m_run + 8.f)) {
                const float nm = fmaxf(m_run, tm);
                const float sc = __builtin_amdgcn_exp2f(m_run - nm);
                m_run = nm;
                l_run *= sc;
                #pragma unroll
                for (int r = 0; r < 16; ++r) { o0[r] *= sc; o1[r] *= sc; }
            }
        }
        #pragma unroll
        for (int r = 0; r < 16; ++r) s[r] = __builtin_amdgcn_exp2f(s[r] - m_run);
        {
            float a8[8];
            #pragma unroll
            for (int r = 0; r < 8; ++r) a8[r] = s[r] + s[r + 8];
            #pragma unroll
            for (int r = 0; r < 4; ++r) a8[r] += a8[r + 4];
            float ps = (a8[0] + a8[1]) + (a8[2] + a8[3]);
            ps += __shfl_xor(ps, 32);
            l_run += ps;
        }
        const unsigned w0 = pk_bf16(s[0], s[1]),   w1 = pk_bf16(s[2], s[3]);
        const unsigned w2 = pk_bf16(s[4], s[5]),   w3 = pk_bf16(s[6], s[7]);
        const unsigned w4 = pk_bf16(s[8], s[9]),   w5 = pk_bf16(s[10], s[11]);
        const unsigned w6 = pk_bf16(s[12], s[13]), w7 = pk_bf16(s[14], s[15]);
        const unsigned e0 = __shfl_xor((int)(hi ? w0 : w2), 32);
        const unsigned e1 = __shfl_xor((int)(hi ? w1 : w3), 32);
        const unsigned e2 = __shfl_xor((int)(hi ? w4 : w6), 32);
        const unsigned e3 = __shfl_xor((int)(hi ? w5 : w7), 32);
        const bf16x8 pf0 = frag4(hi ? e0 : w0, hi ? e1 : w1, hi ? w2 : e0, hi ? w3 : e1);
        const bf16x8 pf1 = frag4(hi ? e2 : w4, hi ? e3 : w5, hi ? w6 : e2, hi ? w7 : e3);
        o0 = MFMA32(v00, pf0, o0);
        o0 = MFMA32(v01, pf1, o0);
        o1 = MFMA32(v10, pf0, o1);
        o1 = MFMA32(v11, pf1, o1);
    };

    STAGE(0, kv0);
    asm volatile("s_waitcnt vmcnt(0)" ::: "memory");
    __builtin_amdgcn_s_barrier();

    for (int tt = 0; tt < 16; ++tt) {
        const int cur = tt & 1;
        if (tt < 15) STAGE(cur ^ 1, kv0 + (tt + 1) * 64);

        #pragma unroll
        for (int s = 0; s < 2; ++s) {        // two 32-kv subtiles
            // K fragments (shared by both q-blocks)
            bf16x8 kf[4];
            #pragma unroll
            for (int ks = 0; ks < 4; ++ks)
                kf[ks] = *(const bf16x8*)&Ks[cur][(s * 32 + lq) * 64 +
                                                  (((ks * 2 + hi) ^ (lq & 7)) * 8)];
            // QK^T for both q-blocks
            f32x16 s0 = {}, s1 = {};
            #pragma unroll
            for (int ks = 0; ks < 4; ++ks) {
                s0 = MFMA32(kf[ks], qfA[ks], s0);
                s1 = MFMA32(kf[ks], qfB[ks], s1);
            }
            // V fragments (shared by both q-blocks)
            const int K0 = s * 4 + hi;
            const int K1 = s * 4 + 2 + hi;
            const bf16x8 v00 = *(const bf16x8*)&Vs[cur][lq * 64 + ((K0 ^ (lq & 7)) * 8)];
            const bf16x8 v10 = *(const bf16x8*)&Vs[cur][(32 + lq) * 64 + ((K0 ^ (lq & 7)) * 8)];
            const bf16x8 v01 = *(const bf16x8*)&Vs[cur][lq * 64 + ((K1 ^ (lq & 7)) * 8)];
            const bf16x8 v11 = *(const bf16x8*)&Vs[cur][(32 + lq) * 64 + ((K1 ^ (lq & 7)) * 8)];

            SMPV(s0, mA, lA, oaA0, oaA1, v00, v01, v10, v11);
            SMPV(s1, mB, lB, oaB0, oaB1, v00, v01, v10, v11);
        }

        asm volatile("s_waitcnt vmcnt(0) lgkmcnt(0)" ::: "memory");
        __builtin_amdgcn_s_barrier();
    }

    // --- epilogue: normalize, pack to B-frag order, store partials ---
    auto EPI = [&](const f32x16& o_0, const f32x16& o_1, float l_run, int nq) {
        const float inv = 1.f / l_run;
        #pragma unroll
        for (int ct = 0; ct < 2; ++ct) {
            f32x16 o = ct ? o_1 : o_0;
            #pragma unroll
            for (int r = 0; r < 16; ++r) o[r] *= inv;
            const unsigned w0 = pk_bf16(o[0], o[1]),   w1 = pk_bf16(o[2], o[3]);
            const unsigned w2 = pk_bf16(o[4], o[5]),   w3 = pk_bf16(o[6], o[7]);
            const unsigned w4 = pk_bf16(o[8], o[9]),   w5 = pk_bf16(o[10], o[11]);
            const unsigned w6 = pk_bf16(o[12], o[13]), w7 = pk_bf16(o[14], o[15]);
            const unsigned e0 = __shfl_xor((int)(hi ? w0 : w2), 32);
            const unsigned e1 = __shfl_xor((int)(hi ? w1 : w3), 32);
            const unsigned e2 = __shfl_xor((int)(hi ? w4 : w6), 32);
            const unsigned e3 = __shfl_xor((int)(hi ? w5 : w7), 32);
            bf16x8 ob0 = frag4(hi ? e0 : w0, hi ? e1 : w1, hi ? w2 : e0, hi ? w3 : e1);
            bf16x8 ob1 = frag4(hi ? e2 : w4, hi ? e3 : w5, hi ? w6 : e2, hi ? w7 : e3);
            bf16_t* op = Opart + (((size_t)(b * 4 + split)) * 4096 + nq) * 64 + ct * 32;
            *(bf16x8*)(op + hi * 8)      = ob0;
            *(bf16x8*)(op + 16 + hi * 8) = ob1;
        }
    };
    EPI(oaA0, oaA1, lA, qA);
    EPI(oaB0, oaB1, lB, qB);

    if (hi == 0) {
        float2 va; va.x = mA; va.y = lA;
        *(float2*)&ml[(((size_t)(b * 4 + split)) * 4096 + qA) * 2] = va;
        float2 vbv; vbv.x = mB; vbv.y = lB;
        *(float2*)&ml[(((size_t)(b * 4 + split)) * 4096 + qB) * 2] = vbv;
    }
}

// ---------------------------------------------------------------------------
// Kernel 3: combine partials + out-proj + bias + skip.
// Grid: (64 q-tiles of 64, 8 batches) = 512 blocks, 512 threads (8 waves).
// ---------------------------------------------------------------------------
__global__ __launch_bounds__(512) void combine_kernel(
    const bf16_t* __restrict__ Opart, const float* __restrict__ ml,
    const float* __restrict__ x, const float* __restrict__ w_out,
    const float* __restrict__ b_out, float* __restrict__ y)
{
    const int b    = blockIdx.y;
    const int t    = threadIdx.x;
    const int lane = t & 63;
    const int wave = t >> 6;          // 0..7
    const int lq   = lane & 31;
    const int hi   = lane >> 5;
    const int group = wave >> 2;      // 0..1
    const int nq   = blockIdx.x * 64 + group * 32 + lq;

    float coef[4];
    {
        float m_s[4], l_s[4];
        #pragma unroll
        for (int s = 0; s < 4; ++s) {
            float2 v = *(const float2*)&ml[(((size_t)(b * 4 + s)) * 4096 + nq) * 2];
            m_s[s] = v.x; l_s[s] = v.y;
        }
        const float M = fmaxf(fmaxf(m_s[0], m_s[1]), fmaxf(m_s[2], m_s[3]));
        float L = 0.f;
        #pragma unroll
        for (int s = 0; s < 4; ++s) {
            coef[s] = __builtin_amdgcn_exp2f(m_s[s] - M) * l_s[s];
            L += coef[s];
        }
        const float invL = 1.f / L;
        #pragma unroll
        for (int s = 0; s < 4; ++s) coef[s] *= invL;
    }

    bf16x8 obf[4];
    #pragma unroll
    for (int ks = 0; ks < 4; ++ks) {
        float a8[8] = {};
        #pragma unroll
        for (int s = 0; s < 4; ++s) {
            bf16x8 o = *(const bf16x8*)&Opart[
                (((size_t)(b * 4 + s)) * 4096 + nq) * 64 + ks * 16 + hi * 8];
            #pragma unroll
            for (int j = 0; j < 8; ++j) a8[j] += coef[s] * (float)o[j];
        }
        obf[ks] = frag4(pk_bf16(a8[0], a8[1]), pk_bf16(a8[2], a8[3]),
                        pk_bf16(a8[4], a8[5]), pk_bf16(a8[6], a8[7]));
    }

    #pragma unroll 1
    for (int i = 0; i < 4; ++i) {
        const int mt = (wave & 3) * 4 + i;
        f32x16 acc = {};
        #pragma unroll
        for (int ks = 0; ks < 4; ++ks) {
            const float* wp = w_out + (size_t)(mt * 32 + lq) * 64 + ks * 16 + hi * 8;
            float4 a0 = *(const float4*)wp;
            float4 a1 = *(const float4*)(wp + 4);
            bf16x8 af = frag4(pk_bf16(a0.x, a0.y), pk_bf16(a0.z, a0.w),
                              pk_bf16(a1.x, a1.y), pk_bf16(a1.z, a1.w));
            acc = MFMA32(af, obf[ks], acc);
        }
        #pragma unroll
        for (int r = 0; r < 16; ++r) {
            const int m = mt * 32 + (r & 3) + 8 * (r >> 2) + 4 * hi;
            const size_t idx = ((size_t)b * 512 + m) * 4096 + nq;
            y[idx] = acc[r] + b_out[m] + x[idx];
        }
    }
}

// ---------------------------------------------------------------------------
extern "C" void kernel_launch(void* const* d_in, const int* in_sizes, int n_in,
                              void* d_out, int out_size, void* d_ws, size_t ws_size,
                              hipStream_t stream)
{
    const float* x     = (const float*)d_in[0];
    const float* w_in  = (const float*)d_in[1];
    const float* b_in  = (const float*)d_in[2];
    const float* w_out = (const float*)d_in[3];
    const float* b_out = (const float*)d_in[4];
    float* y = (float*)d_out;

    char* ws = (char*)d_ws;
    bf16_t* q_r   = (bf16_t*)(ws);                   // 4 MiB
    bf16_t* k_r   = (bf16_t*)(ws + 4194304);         // 4 MiB
    bf16_t* v_t   = (bf16_t*)(ws + 8388608);         // 4 MiB
    bf16_t* Opart = (bf16_t*)(ws + 12582912);        // 8*4*4096*64*2 = 16 MiB
    float*  ml    = (float*)(ws + 29360128);         // 8*4*4096*2*4  = 1 MiB

    qkv_kernel<<<dim3(64, 3, 8), 256, 0, stream>>>(x, w_in, b_in, q_r, k_r, v_t);
    attn_partial_kernel<<<dim3(16, 8, 4), 256, 0, stream>>>(q_r, k_r, v_t, Opart, ml);
    combine_kernel<<<dim3(64, 8), 512, 0, stream>>>(Opart, ml, x, w_out, b_out, y);
}

// Round 7
// 131.244 us; speedup vs baseline: 1.7183x; 1.1879x over previous
//
#include <hip/hip_runtime.h>
#include <hip/hip_bf16.h>

typedef __bf16 bf16_t;
typedef __bf16 bf16x8 __attribute__((ext_vector_type(8)));
typedef float f32x4 __attribute__((ext_vector_type(4)));
typedef float f32x16 __attribute__((ext_vector_type(16)));
typedef unsigned int u32x4 __attribute__((ext_vector_type(4)));

#define MFMA16(A,B,C) __builtin_amdgcn_mfma_f32_16x16x32_bf16(A,B,C,0,0,0)
#define MFMA32(A,B,C) __builtin_amdgcn_mfma_f32_32x32x16_bf16(A,B,C,0,0,0)

// exp(s/8) computed as exp2(s * 0.125*log2(e)); the scale is folded into Q.
#define QSCALE 0.18033688011112042f

__device__ inline unsigned pk_bf16(float lo, float hi) {
  unsigned r;
  asm("v_cvt_pk_bf16_f32 %0, %1, %2" : "=v"(r) : "v"(lo), "v"(hi));
  return r;
}
__device__ inline bf16x8 frag4(unsigned a, unsigned b, unsigned c, unsigned d) {
  union { u32x4 u; bf16x8 f; } x;
  x.u = (u32x4){a, b, c, d};
  return x.f;
}
__device__ inline void gload16(const bf16_t* g, const bf16_t* l) {
  __builtin_amdgcn_global_load_lds(
      (const __attribute__((address_space(1))) unsigned int*)g,
      (__attribute__((address_space(3))) unsigned int*)l, 16, 0, 0);
}

// ---------------------------------------------------------------------------
// Kernel 1 (v3): qkv = w_in @ x + b_in, ONE block per (n-tile, batch).
// All 192 out-channels per block: x-tile staged ONCE (vs 3x in round 5).
// Double-buffered Xs[2][64][56] ([buf][n][k], 112B rows), BK=32, register
// prefetch, one barrier/iter. Staging layout/stores identical to the proven
// round-5 pattern (scalar transposed bf16 writes).
// Wave w computes m = w*48 .. w*48+48 (3 x 16-row frags) x 64 n.
// Q -> q_r [8][4096][64] bf16 PRE-SCALED by 0.125*log2(e)
// K -> k_r [8][4096][64] bf16;  V -> v_t [8][64][4096] bf16
// Grid: (64, 8), 256 threads.
// ---------------------------------------------------------------------------
__global__ __launch_bounds__(256, 4) void qkv_kernel(
    const float* __restrict__ x,
    const float* __restrict__ w_in,
    const float* __restrict__ b_in,
    bf16_t* __restrict__ q_r,
    bf16_t* __restrict__ k_r,
    bf16_t* __restrict__ v_t)
{
    const int b    = blockIdx.y;
    const int n0   = blockIdx.x * 64;
    const int t    = threadIdx.x;
    const int lane = t & 63;
    const int wave = t >> 6;

    __shared__ bf16_t Xs[2][64][56];      // [buf][n][k], row stride 112B

    const float* xb = x + (size_t)b * 512 * 4096;

    // staging decomposition (round-5 proven): thread -> k-row c, n-octet nb
    const int c  = t >> 3;                // 0..31
    const int nb = (t & 7) * 8;           // 0..56

    float4 pv0, pv1;                      // prefetch registers (1 k-row x 8 n)

    // prologue: tile 0
    {
        const float* src = xb + (size_t)c * 4096 + n0 + nb;
        pv0 = *(const float4*)(src);
        pv1 = *(const float4*)(src + 4);
        Xs[0][nb + 0][c] = (bf16_t)pv0.x; Xs[0][nb + 1][c] = (bf16_t)pv0.y;
        Xs[0][nb + 2][c] = (bf16_t)pv0.z; Xs[0][nb + 3][c] = (bf16_t)pv0.w;
        Xs[0][nb + 4][c] = (bf16_t)pv1.x; Xs[0][nb + 5][c] = (bf16_t)pv1.y;
        Xs[0][nb + 6][c] = (bf16_t)pv1.z; Xs[0][nb + 7][c] = (bf16_t)pv1.w;
    }
    __syncthreads();

    f32x4 acc[3][4] = {};                 // [mf][nf]

    for (int kk = 0; kk < 16; ++kk) {
        const int cur = kk & 1;
        if (kk < 15) {                    // prefetch next tile into registers
            const float* src = xb + (size_t)((kk + 1) * 32 + c) * 4096 + n0 + nb;
            pv0 = *(const float4*)(src);
            pv1 = *(const float4*)(src + 4);
        }

        // B-frags: col n, k = (lane>>4)*8 + j  (16B-aligned contiguous reads)
        bf16x8 bfr[4];
        #pragma unroll
        for (int nf = 0; nf < 4; ++nf)
            bfr[nf] = *(const bf16x8*)&Xs[cur][nf * 16 + (lane & 15)][(lane >> 4) * 8];

        // A-frags from w_in (fp32 -> bf16); rows L1-resident across iters
        #pragma unroll
        for (int mf = 0; mf < 3; ++mf) {
            const int m = wave * 48 + mf * 16 + (lane & 15);
            const float* wsrc = w_in + (size_t)m * 512 + kk * 32 + (lane >> 4) * 8;
            f32x4 a0 = *(const f32x4*)(wsrc);
            f32x4 a1 = *(const f32x4*)(wsrc + 4);
            bf16x8 af = frag4(pk_bf16(a0[0], a0[1]), pk_bf16(a0[2], a0[3]),
                              pk_bf16(a1[0], a1[1]), pk_bf16(a1[2], a1[3]));
            #pragma unroll
            for (int nf = 0; nf < 4; ++nf)
                acc[mf][nf] = MFMA16(af, bfr[nf], acc[mf][nf]);
        }

        if (kk < 15) {                    // write next tile into other buffer
            const int nxt = cur ^ 1;
            Xs[nxt][nb + 0][c] = (bf16_t)pv0.x; Xs[nxt][nb + 1][c] = (bf16_t)pv0.y;
            Xs[nxt][nb + 2][c] = (bf16_t)pv0.z; Xs[nxt][nb + 3][c] = (bf16_t)pv0.w;
            Xs[nxt][nb + 4][c] = (bf16_t)pv1.x; Xs[nxt][nb + 5][c] = (bf16_t)pv1.y;
            Xs[nxt][nb + 6][c] = (bf16_t)pv1.z; Xs[nxt][nb + 7][c] = (bf16_t)pv1.w;
        }
        __syncthreads();
    }

    // epilogue: + bias, route channel block to Q/K/V (scalar stores, proven)
    #pragma unroll
    for (int mf = 0; mf < 3; ++mf) {
        const int mbase = wave * 48 + mf * 16;        // 16-aligned block base
        const int route = mbase >> 6;                 // 0:Q 1:K 2:V (wave-uniform)
        const int cloc  = (mbase & 63) + (lane >> 4) * 4;  // local channel base
        const int bbase = mbase + (lane >> 4) * 4;    // global bias base
        #pragma unroll
        for (int nf = 0; nf < 4; ++nf) {
            const int n = n0 + nf * 16 + (lane & 15);
            const float v0 = acc[mf][nf][0] + b_in[bbase + 0];
            const float v1 = acc[mf][nf][1] + b_in[bbase + 1];
            const float v2 = acc[mf][nf][2] + b_in[bbase + 2];
            const float v3 = acc[mf][nf][3] + b_in[bbase + 3];
            if (route == 0) {
                bf16_t* qp = &q_r[((size_t)b * 4096 + n) * 64 + cloc];
                qp[0] = (bf16_t)(v0 * QSCALE); qp[1] = (bf16_t)(v1 * QSCALE);
                qp[2] = (bf16_t)(v2 * QSCALE); qp[3] = (bf16_t)(v3 * QSCALE);
            } else if (route == 1) {
                bf16_t* kp = &k_r[((size_t)b * 4096 + n) * 64 + cloc];
                kp[0] = (bf16_t)v0; kp[1] = (bf16_t)v1;
                kp[2] = (bf16_t)v2; kp[3] = (bf16_t)v3;
            } else {
                v_t[((size_t)b * 64 + cloc + 0) * 4096 + n] = (bf16_t)v0;
                v_t[((size_t)b * 64 + cloc + 1) * 4096 + n] = (bf16_t)v1;
                v_t[((size_t)b * 64 + cloc + 2) * 4096 + n] = (bf16_t)v2;
                v_t[((size_t)b * 64 + cloc + 3) * 4096 + n] = (bf16_t)v3;
            }
        }
    }
}

// ---------------------------------------------------------------------------
// Kernel 2: flash attention PARTIAL (KV-split by 4), LDS-staged, 64 q/wave.
// Grid: (16 q-tiles of 256, 8 batches, 4 splits) = 512 blocks, 256 threads.
// (byte-identical to the passing round-5 version)
// ---------------------------------------------------------------------------
__global__ __launch_bounds__(256, 2) void attn_partial_kernel(
    const bf16_t* __restrict__ q_r, const bf16_t* __restrict__ k_r,
    const bf16_t* __restrict__ v_t,
    bf16_t* __restrict__ Opart, float* __restrict__ ml)
{
    const int b     = blockIdx.y;
    const int split = blockIdx.z;
    const int kv0   = split * 1024;
    const int t     = threadIdx.x;
    const int lane  = t & 63;
    const int wave  = t >> 6;
    const int lq    = lane & 31;
    const int hi    = lane >> 5;
    const int qA    = blockIdx.x * 256 + wave * 64 + lq;
    const int qB    = qA + 32;

    __shared__ bf16_t Ks[2][64 * 64];
    __shared__ bf16_t Vs[2][64 * 64];

    const int r8  = lane >> 3;
    const int csw = (lane & 7) ^ r8;
    const bf16_t* kb = k_r + (size_t)b * 4096 * 64;
    const bf16_t* vb = v_t + (size_t)b * 64 * 4096;

    auto STAGE = [&](int buf, int m0) {
        #pragma unroll
        for (int i = 0; i < 2; ++i) {
            const int rr = wave * 16 + i * 8;
            gload16(kb + (size_t)(m0 + rr + r8) * 64 + csw * 8, &Ks[buf][rr * 64]);
            gload16(vb + (size_t)(rr + r8) * 4096 + m0 + csw * 8, &Vs[buf][rr * 64]);
        }
    };

    bf16x8 qfA[4], qfB[4];
    {
        const bf16_t* qpA = q_r + ((size_t)b * 4096 + qA) * 64 + hi * 8;
        const bf16_t* qpB = q_r + ((size_t)b * 4096 + qB) * 64 + hi * 8;
        #pragma unroll
        for (int ks = 0; ks < 4; ++ks) {
            qfA[ks] = *(const bf16x8*)(qpA + ks * 16);
            qfB[ks] = *(const bf16x8*)(qpB + ks * 16);
        }
    }

    f32x16 oaA0 = {}, oaA1 = {}, oaB0 = {}, oaB1 = {};
    float mA = -3.0e38f, lA = 0.f, mB = -3.0e38f, lB = 0.f;

    auto SMPV = [&](f32x16& s, float& m_run, float& l_run,
                    f32x16& o0, f32x16& o1,
                    const bf16x8 v00, const bf16x8 v01,
                    const bf16x8 v10, const bf16x8 v11) {
        {
            float a8[8];
            #pragma unroll
            for (int r = 0; r < 8; ++r) a8[r] = fmaxf(s[r], s[r + 8]);
            #pragma unroll
            for (int r = 0; r < 4; ++r) a8[r] = fmaxf(a8[r], a8[r + 4]);
            float tm = fmaxf(fmaxf(a8[0], a8[1]), fmaxf(a8[2], a8[3]));
            tm = fmaxf(tm, __shfl_xor(tm, 32));
            if (__any(tm > m_run + 8.f)) {
                const float nm = fmaxf(m_run, tm);
                const float sc = __builtin_amdgcn_exp2f(m_run - nm);
                m_run = nm;
                l_run *= sc;
                #pragma unroll
                for (int r = 0; r < 16; ++r) { o0[r] *= sc; o1[r] *= sc; }
            }
        }
        #pragma unroll
        for (int r = 0; r < 16; ++r) s[r] = __builtin_amdgcn_exp2f(s[r] - m_run);
        {
            float a8[8];
            #pragma unroll
            for (int r = 0; r < 8; ++r) a8[r] = s[r] + s[r + 8];
            #pragma unroll
            for (int r = 0; r < 4; ++r) a8[r] += a8[r + 4];
            float ps = (a8[0] + a8[1]) + (a8[2] + a8[3]);
            ps += __shfl_xor(ps, 32);
            l_run += ps;
        }
        const unsigned w0 = pk_bf16(s[0], s[1]),   w1 = pk_bf16(s[2], s[3]);
        const unsigned w2 = pk_bf16(s[4], s[5]),   w3 = pk_bf16(s[6], s[7]);
        const unsigned w4 = pk_bf16(s[8], s[9]),   w5 = pk_bf16(s[10], s[11]);
        const unsigned w6 = pk_bf16(s[12], s[13]), w7 = pk_bf16(s[14], s[15]);
        const unsigned e0 = __shfl_xor((int)(hi ? w0 : w2), 32);
        const unsigned e1 = __shfl_xor((int)(hi ? w1 : w3), 32);
        const unsigned e2 = __shfl_xor((int)(hi ? w4 : w6), 32);
        const unsigned e3 = __shfl_xor((int)(hi ? w5 : w7), 32);
        const bf16x8 pf0 = frag4(hi ? e0 : w0, hi ? e1 : w1, hi ? w2 : e0, hi ? w3 : e1);
        const bf16x8 pf1 = frag4(hi ? e2 : w4, hi ? e3 : w5, hi ? w6 : e2, hi ? w7 : e3);
        o0 = MFMA32(v00, pf0, o0);
        o0 = MFMA32(v01, pf1, o0);
        o1 = MFMA32(v10, pf0, o1);
        o1 = MFMA32(v11, pf1, o1);
    };

    STAGE(0, kv0);
    asm volatile("s_waitcnt vmcnt(0)" ::: "memory");
    __builtin_amdgcn_s_barrier();

    for (int tt = 0; tt < 16; ++tt) {
        const int cur = tt & 1;
        if (tt < 15) STAGE(cur ^ 1, kv0 + (tt + 1) * 64);

        #pragma unroll
        for (int s = 0; s < 2; ++s) {
            bf16x8 kf[4];
            #pragma unroll
            for (int ks = 0; ks < 4; ++ks)
                kf[ks] = *(const bf16x8*)&Ks[cur][(s * 32 + lq) * 64 +
                                                  (((ks * 2 + hi) ^ (lq & 7)) * 8)];
            f32x16 s0 = {}, s1 = {};
            #pragma unroll
            for (int ks = 0; ks < 4; ++ks) {
                s0 = MFMA32(kf[ks], qfA[ks], s0);
                s1 = MFMA32(kf[ks], qfB[ks], s1);
            }
            const int K0 = s * 4 + hi;
            const int K1 = s * 4 + 2 + hi;
            const bf16x8 v00 = *(const bf16x8*)&Vs[cur][lq * 64 + ((K0 ^ (lq & 7)) * 8)];
            const bf16x8 v10 = *(const bf16x8*)&Vs[cur][(32 + lq) * 64 + ((K0 ^ (lq & 7)) * 8)];
            const bf16x8 v01 = *(const bf16x8*)&Vs[cur][lq * 64 + ((K1 ^ (lq & 7)) * 8)];
            const bf16x8 v11 = *(const bf16x8*)&Vs[cur][(32 + lq) * 64 + ((K1 ^ (lq & 7)) * 8)];

            SMPV(s0, mA, lA, oaA0, oaA1, v00, v01, v10, v11);
            SMPV(s1, mB, lB, oaB0, oaB1, v00, v01, v10, v11);
        }

        asm volatile("s_waitcnt vmcnt(0) lgkmcnt(0)" ::: "memory");
        __builtin_amdgcn_s_barrier();
    }

    auto EPI = [&](const f32x16& o_0, const f32x16& o_1, float l_run, int nq) {
        const float inv = 1.f / l_run;
        #pragma unroll
        for (int ct = 0; ct < 2; ++ct) {
            f32x16 o = ct ? o_1 : o_0;
            #pragma unroll
            for (int r = 0; r < 16; ++r) o[r] *= inv;
            const unsigned w0 = pk_bf16(o[0], o[1]),   w1 = pk_bf16(o[2], o[3]);
            const unsigned w2 = pk_bf16(o[4], o[5]),   w3 = pk_bf16(o[6], o[7]);
            const unsigned w4 = pk_bf16(o[8], o[9]),   w5 = pk_bf16(o[10], o[11]);
            const unsigned w6 = pk_bf16(o[12], o[13]), w7 = pk_bf16(o[14], o[15]);
            const unsigned e0 = __shfl_xor((int)(hi ? w0 : w2), 32);
            const unsigned e1 = __shfl_xor((int)(hi ? w1 : w3), 32);
            const unsigned e2 = __shfl_xor((int)(hi ? w4 : w6), 32);
            const unsigned e3 = __shfl_xor((int)(hi ? w5 : w7), 32);
            bf16x8 ob0 = frag4(hi ? e0 : w0, hi ? e1 : w1, hi ? w2 : e0, hi ? w3 : e1);
            bf16x8 ob1 = frag4(hi ? e2 : w4, hi ? e3 : w5, hi ? w6 : e2, hi ? w7 : e3);
            bf16_t* op = Opart + (((size_t)(b * 4 + split)) * 4096 + nq) * 64 + ct * 32;
            *(bf16x8*)(op + hi * 8)      = ob0;
            *(bf16x8*)(op + 16 + hi * 8) = ob1;
        }
    };
    EPI(oaA0, oaA1, lA, qA);
    EPI(oaB0, oaB1, lB, qB);

    if (hi == 0) {
        float2 va; va.x = mA; va.y = lA;
        *(float2*)&ml[(((size_t)(b * 4 + split)) * 4096 + qA) * 2] = va;
        float2 vbv; vbv.x = mB; vbv.y = lB;
        *(float2*)&ml[(((size_t)(b * 4 + split)) * 4096 + qB) * 2] = vbv;
    }
}

// ---------------------------------------------------------------------------
// Kernel 3: combine partials + out-proj + bias + skip.
// Grid: (64 q-tiles of 64, 8 batches) = 512 blocks, 512 threads (8 waves).
// (byte-identical to the passing round-5 version)
// ---------------------------------------------------------------------------
__global__ __launch_bounds__(512) void combine_kernel(
    const bf16_t* __restrict__ Opart, const float* __restrict__ ml,
    const float* __restrict__ x, const float* __restrict__ w_out,
    const float* __restrict__ b_out, float* __restrict__ y)
{
    const int b    = blockIdx.y;
    const int t    = threadIdx.x;
    const int lane = t & 63;
    const int wave = t >> 6;          // 0..7
    const int lq   = lane & 31;
    const int hi   = lane >> 5;
    const int group = wave >> 2;      // 0..1
    const int nq   = blockIdx.x * 64 + group * 32 + lq;

    float coef[4];
    {
        float m_s[4], l_s[4];
        #pragma unroll
        for (int s = 0; s < 4; ++s) {
            float2 v = *(const float2*)&ml[(((size_t)(b * 4 + s)) * 4096 + nq) * 2];
            m_s[s] = v.x; l_s[s] = v.y;
        }
        const float M = fmaxf(fmaxf(m_s[0], m_s[1]), fmaxf(m_s[2], m_s[3]));
        float L = 0.f;
        #pragma unroll
        for (int s = 0; s < 4; ++s) {
            coef[s] = __builtin_amdgcn_exp2f(m_s[s] - M) * l_s[s];
            L += coef[s];
        }
        const float invL = 1.f / L;
        #pragma unroll
        for (int s = 0; s < 4; ++s) coef[s] *= invL;
    }

    bf16x8 obf[4];
    #pragma unroll
    for (int ks = 0; ks < 4; ++ks) {
        float a8[8] = {};
        #pragma unroll
        for (int s = 0; s < 4; ++s) {
            bf16x8 o = *(const bf16x8*)&Opart[
                (((size_t)(b * 4 + s)) * 4096 + nq) * 64 + ks * 16 + hi * 8];
            #pragma unroll
            for (int j = 0; j < 8; ++j) a8[j] += coef[s] * (float)o[j];
        }
        obf[ks] = frag4(pk_bf16(a8[0], a8[1]), pk_bf16(a8[2], a8[3]),
                        pk_bf16(a8[4], a8[5]), pk_bf16(a8[6], a8[7]));
    }

    #pragma unroll 1
    for (int i = 0; i < 4; ++i) {
        const int mt = (wave & 3) * 4 + i;
        f32x16 acc = {};
        #pragma unroll
        for (int ks = 0; ks < 4; ++ks) {
            const float* wp = w_out + (size_t)(mt * 32 + lq) * 64 + ks * 16 + hi * 8;
            f32x4 a0 = *(const f32x4*)wp;
            f32x4 a1 = *(const f32x4*)(wp + 4);
            bf16x8 af = frag4(pk_bf16(a0[0], a0[1]), pk_bf16(a0[2], a0[3]),
                              pk_bf16(a1[0], a1[1]), pk_bf16(a1[2], a1[3]));
            acc = MFMA32(af, obf[ks], acc);
        }
        #pragma unroll
        for (int r = 0; r < 16; ++r) {
            const int m = mt * 32 + (r & 3) + 8 * (r >> 2) + 4 * hi;
            const size_t idx = ((size_t)b * 512 + m) * 4096 + nq;
            y[idx] = acc[r] + b_out[m] + x[idx];
        }
    }
}

// ---------------------------------------------------------------------------
extern "C" void kernel_launch(void* const* d_in, const int* in_sizes, int n_in,
                              void* d_out, int out_size, void* d_ws, size_t ws_size,
                              hipStream_t stream)
{
    const float* x     = (const float*)d_in[0];
    const float* w_in  = (const float*)d_in[1];
    const float* b_in  = (const float*)d_in[2];
    const float* w_out = (const float*)d_in[3];
    const float* b_out = (const float*)d_in[4];
    float* y = (float*)d_out;

    char* ws = (char*)d_ws;
    bf16_t* q_r   = (bf16_t*)(ws);                   // 4 MiB
    bf16_t* k_r   = (bf16_t*)(ws + 4194304);         // 4 MiB
    bf16_t* v_t   = (bf16_t*)(ws + 8388608);         // 4 MiB
    bf16_t* Opart = (bf16_t*)(ws + 12582912);        // 8*4*4096*64*2 = 16 MiB
    float*  ml    = (float*)(ws + 29360128);         // 8*4*4096*2*4  = 1 MiB

    qkv_kernel<<<dim3(64, 8), 256, 0, stream>>>(x, w_in, b_in, q_r, k_r, v_t);
    attn_partial_kernel<<<dim3(16, 8, 4), 256, 0, stream>>>(q_r, k_r, v_t, Opart, ml);
    combine_kernel<<<dim3(64, 8), 512, 0, stream>>>(Opart, ml, x, w_out, b_out, y);
}